// Round 12
// baseline (114.684 us; speedup 1.0000x reference)
//
#include <hip/hip_runtime.h>
#include <math.h>

#define NROWS 4096
#define DDIM  256
#define BM 128
#define BN 256
#define BK 64
#define NTM (NROWS / BM)   // 32 M-tiles
#define NTN (NROWS / BN)   // 16 N-tiles
#define NRP (NTN * 2)      // 32 row-partial slices (per N-tile x wc-half)
#define NCP (NTM * 2)      // 64 col-partial slices (per M-tile x wr-half)
#define LOG2E2 2.8853900817779268f   // 2*log2(e): exp(2S) = exp2(LOG2E2 * S)

typedef __attribute__((ext_vector_type(4))) float f32x4;   // MFMA 16x16 C/D

__device__ __forceinline__ float exp2_fast(float x) {
#if __has_builtin(__builtin_amdgcn_exp2f)
    return __builtin_amdgcn_exp2f(x);
#else
    return exp2f(x);
#endif
}

// ---- float -> fp8 e4m3 (OCP) ----
__device__ __forceinline__ unsigned char f2e4m3(float f) {
    unsigned int u = __float_as_uint(f);
    unsigned int s = (u >> 24) & 0x80;
    float a = fabsf(f);
    if (a >= 448.0f) return (unsigned char)(s | 0x7E);
    if (a < 0.0009765625f) return (unsigned char)s;        // < 2^-10 -> 0
    int exp = (int)((u >> 23) & 0xFF) - 127;
    if (exp < -6) {                                        // subnormal: units of 2^-9
        int t = (int)(a * 512.0f + 0.5f);
        return (unsigned char)(s | (unsigned char)t);
    }
    unsigned int r = u + 0x0007FFFF + ((u >> 20) & 1);     // RNE to 3 mantissa bits
    exp = (int)((r >> 23) & 0xFF) - 127;
    if (exp > 8) return (unsigned char)(s | 0x7E);
    unsigned int mant = (r >> 20) & 7;
    return (unsigned char)(s | (unsigned int)((exp + 7) << 3) | mant);
}

__device__ __forceinline__ unsigned int pack4_e4m3(float a, float b, float c, float d) {
#if __has_builtin(__builtin_amdgcn_cvt_pk_fp8_f32)
    int v = __builtin_amdgcn_cvt_pk_fp8_f32(a, b, 0, 0);       // bytes 0,1
    v = __builtin_amdgcn_cvt_pk_fp8_f32(c, d, v, 1);           // bytes 2,3
    return (unsigned int)v;
#else
    return (unsigned int)f2e4m3(a) | ((unsigned int)f2e4m3(b) << 8) |
           ((unsigned int)f2e4m3(c) << 16) | ((unsigned int)f2e4m3(d) << 24);
#endif
}

// global -> LDS direct DMA, 16B per lane. LDS dest is wave-uniform base
// (lane offset implicit +lane*16); global src is per-lane (pre-swizzled).
#define GLOAD_LDS16(gsrc, ldst)                                          \
    __builtin_amdgcn_global_load_lds(                                    \
        (__attribute__((address_space(1))) void*)(gsrc),                 \
        (__attribute__((address_space(3))) void*)(ldst), 16, 0, 0)

// ---------------- Kernel 1: L2-normalize rows + positive dots ----------------
// 1 wave per row. pos computed in fp32 (exact); fp8 e4m3 copies for MFMA.
// A-side (zi) pre-scaled by 2*log2(e) so the GEMM accumulator is exp2-ready.
__global__ __launch_bounds__(256) void normalize_kernel(
    const float* __restrict__ emb_i, const float* __restrict__ emb_j,
    unsigned char* __restrict__ zi, unsigned char* __restrict__ zj,
    float* __restrict__ pos)
{
    const int wave = threadIdx.x >> 6;
    const int lane = threadIdx.x & 63;
    const int row  = blockIdx.x * 4 + wave;

    const float4 vi = *((const float4*)(emb_i + (size_t)row * DDIM) + lane);
    const float4 vj = *((const float4*)(emb_j + (size_t)row * DDIM) + lane);

    float ssi = vi.x*vi.x + vi.y*vi.y + vi.z*vi.z + vi.w*vi.w;
    float ssj = vj.x*vj.x + vj.y*vj.y + vj.z*vj.z + vj.w*vj.w;
    #pragma unroll
    for (int m = 1; m < 64; m <<= 1) {
        ssi += __shfl_xor(ssi, m);
        ssj += __shfl_xor(ssj, m);
    }
    const float ri = 1.0f / fmaxf(sqrtf(ssi), 1e-12f);
    const float rj = 1.0f / fmaxf(sqrtf(ssj), 1e-12f);

    const float zix = vi.x*ri, ziy = vi.y*ri, ziz = vi.z*ri, ziw = vi.w*ri;
    const float zjx = vj.x*rj, zjy = vj.y*rj, zjz = vj.z*rj, zjw = vj.w*rj;

    float p = zix*zjx + ziy*zjy + ziz*zjz + ziw*zjw;
    #pragma unroll
    for (int m = 1; m < 64; m <<= 1) p += __shfl_xor(p, m);
    if (lane == 0) pos[row] = p;

    *(unsigned int*)(zi + (size_t)row * DDIM + lane * 4) =
        pack4_e4m3(zix*LOG2E2, ziy*LOG2E2, ziz*LOG2E2, ziw*LOG2E2);
    *(unsigned int*)(zj + (size_t)row * DDIM + lane * 4) =
        pack4_e4m3(zjx, zjy, zjz, zjw);
}

// ---------- Kernel 2: fp8 MFMA S-tile + exp2 + ATOMIC-FREE partial sums ------
// R6/R10-optimal structure (128x256 tile, 4 waves 2x2, 2 blocks/CU, 512 blocks
// all co-resident). Epilogue: per-WAVE disjoint partial slices (R11's race was
// waves sharing wc/wr writing the same address; now slice index includes the
// wave-half): rowpart[(by*2+wc)][bm+...], colpart[(bx*2+wr)][bn+...]. Every
// address written by exactly one lane. Zero atomics, zero init required.
__global__ __launch_bounds__(256, 2) void gemm_fused_kernel(
    const unsigned char* __restrict__ zi, const unsigned char* __restrict__ zj,
    float* __restrict__ rowpart, float* __restrict__ colpart)
{
    __shared__ unsigned char As[BM * BK];   // 8 KiB
    __shared__ unsigned char Bs[BN * BK];   // 16 KiB

    const int tid  = threadIdx.x;
    const int lane = tid & 63;
    const int wave = tid >> 6;     // 0..3
    const int g    = lane >> 4;    // k-group 0..3
    const int fr   = lane & 15;    // fragment row 0..15
    const int wr   = wave >> 1;    // wave row 0..1 (64-row halves)
    const int wc   = wave & 1;     // wave col 0..1 (128-col halves)
    const int bm   = blockIdx.x * BM;
    const int bn   = blockIdx.y * BN;

    f32x4 acc[4][8] = {};          // 128 VGPR; all indices compile-time

    for (int k0 = 0; k0 < DDIM; k0 += BK) {
        // A: 128 rows x 4 slots = 512 granules = 2 rounds of 256 threads.
        #pragma unroll
        for (int it = 0; it < 2; ++it) {
            const int L   = it * 256 + tid;
            const int row = L >> 2;
            const int sl  = (L & 3) ^ (row & 3);
            GLOAD_LDS16(zi + (size_t)(bm + row) * DDIM + k0 + sl * 16,
                        &As[(it * 256 + wave * 64) * 16]);
        }
        // B: 256 rows x 4 slots = 1024 granules = 4 rounds.
        #pragma unroll
        for (int it = 0; it < 4; ++it) {
            const int L   = it * 256 + tid;
            const int row = L >> 2;
            const int sl  = (L & 3) ^ (row & 3);
            GLOAD_LDS16(zj + (size_t)(bn + row) * DDIM + k0 + sl * 16,
                        &Bs[(it * 256 + wave * 64) * 16]);
        }
        __syncthreads();   // drain staging (compiler emits vmcnt(0) first)

        #pragma unroll
        for (int kk = 0; kk < 2; ++kk) {
            // lane's 8 bytes: k = kk*32 + g*8 -> slot = kk*2 + (g>>1),
            // byte-in-slot = (g&1)*8; un-swizzle slot with fr&3 (== row&3).
            const int slot = kk * 2 + (g >> 1);
            const int boff = ((slot ^ (fr & 3)) << 4) + ((g & 1) << 3);
            long long a[4], b[8];
            #pragma unroll
            for (int mi = 0; mi < 4; ++mi)
                a[mi] = *(const long long*)&As[(wr * 64 + mi * 16 + fr) * BK + boff];
            #pragma unroll
            for (int ni = 0; ni < 8; ++ni)
                b[ni] = *(const long long*)&Bs[(wc * 128 + ni * 16 + fr) * BK + boff];
            #pragma unroll
            for (int mi = 0; mi < 4; ++mi)
                #pragma unroll
                for (int ni = 0; ni < 8; ++ni)
                    acc[mi][ni] = __builtin_amdgcn_mfma_f32_16x16x32_fp8_fp8(
                        a[mi], b[ni], acc[mi][ni], 0, 0, 0);
        }
        __syncthreads();   // WAR: single-buffer reuse next K-iter
    }

    // Epilogue. acc[mi][ni][j] = LOG2E2 * S at row bm+wr*64+mi*16+g*4+j,
    // col bn+wc*128+ni*16+fr (C/D layout dtype-independent, verified R3-R10).
    float rp[4][4];
    float cp[8] = {0.f,0.f,0.f,0.f,0.f,0.f,0.f,0.f};
    #pragma unroll
    for (int mi = 0; mi < 4; ++mi)
        #pragma unroll
        for (int j = 0; j < 4; ++j) rp[mi][j] = 0.f;

    #pragma unroll
    for (int mi = 0; mi < 4; ++mi)
        #pragma unroll
        for (int ni = 0; ni < 8; ++ni)
            #pragma unroll
            for (int j = 0; j < 4; ++j) {
                const float e = exp2_fast(acc[mi][ni][j]);
                rp[mi][j] += e;
                cp[ni]    += e;
            }

    // Row sums -> rowpart[by*2+wc][bm+...]: reduce over cols = lane bits 0..3;
    // lanes fr==0 (g=0..3) store rows g*4+j. Slice unique per (by,wc); rows
    // unique per (bx, wr, mi, g, j). No races.
    float* rslice = rowpart + (size_t)(blockIdx.y * 2 + wc) * NROWS + bm;
    #pragma unroll
    for (int mi = 0; mi < 4; ++mi)
        #pragma unroll
        for (int j = 0; j < 4; ++j) {
            float v = rp[mi][j];
            v += __shfl_xor(v, 1); v += __shfl_xor(v, 2);
            v += __shfl_xor(v, 4); v += __shfl_xor(v, 8);
            if (fr == 0)
                rslice[wr * 64 + mi * 16 + g * 4 + j] = v;
        }

    // Col sums -> colpart[bx*2+wr][bn+...]: reduce over lane bits 4,5; lanes
    // g==0 store 16 consecutive cols. Slice unique per (bx,wr); cols unique
    // per (by, wc, ni, fr). No races.
    float* cslice = colpart + (size_t)(blockIdx.x * 2 + wr) * NROWS + bn;
    #pragma unroll
    for (int ni = 0; ni < 8; ++ni) {
        float v = cp[ni];
        v += __shfl_xor(v, 16); v += __shfl_xor(v, 32);
        if (g == 0)
            cslice[wc * 128 + ni * 16 + fr] = v;
    }
}

// ---------------- Kernel 3: final reduction (atomic-free) ----------------
// 1024 threads; for fixed slice t, lane-adjacent rows r are coalesced.
__global__ __launch_bounds__(1024) void finalize_kernel(
    const float* __restrict__ pos, const float* __restrict__ rowpart,
    const float* __restrict__ colpart, float* __restrict__ out)
{
    float s = 0.0f;
    for (int r = threadIdx.x; r < NROWS; r += 1024) {
        float rs = 0.f, cs = 0.f;
        #pragma unroll
        for (int t = 0; t < NRP; ++t) rs += rowpart[(size_t)t * NROWS + r];
        #pragma unroll
        for (int t = 0; t < NCP; ++t) cs += colpart[(size_t)t * NROWS + r];
        // log(0.5*rs) + log(0.5*cs) = log(0.25*rs*cs)
        s += -4.0f * pos[r] + logf(0.25f * rs * cs);
    }
    __shared__ float part[16];
    #pragma unroll
    for (int m = 1; m < 64; m <<= 1) s += __shfl_xor(s, m);
    if ((threadIdx.x & 63) == 0) part[threadIdx.x >> 6] = s;
    __syncthreads();
    if (threadIdx.x == 0) {
        float t = 0.f;
        #pragma unroll
        for (int w = 0; w < 16; ++w) t += part[w];
        out[0] = t / (2.0f * NROWS);
    }
}

extern "C" void kernel_launch(void* const* d_in, const int* in_sizes, int n_in,
                              void* d_out, int out_size, void* d_ws, size_t ws_size,
                              hipStream_t stream)
{
    const float* emb_i = (const float*)d_in[0];
    const float* emb_j = (const float*)d_in[1];

    unsigned char* zi = (unsigned char*)d_ws;                 // N*D fp8 (scaled)
    unsigned char* zj = zi + (size_t)NROWS * DDIM;            // N*D fp8
    float* pos     = (float*)(zj + (size_t)NROWS * DDIM);     // N
    float* rowpart = pos + NROWS;                             // NRP x N = 128K
    float* colpart = rowpart + (size_t)NRP * NROWS;           // NCP x N = 256K

    normalize_kernel<<<NROWS / 4, 256, 0, stream>>>(emb_i, emb_j, zi, zj, pos);

    dim3 grid(NTM, NTN);   // 32 x 16 = 512 blocks, 2/CU, 1 round
    gemm_fused_kernel<<<grid, 256, 0, stream>>>(zi, zj, rowpart, colpart);

    finalize_kernel<<<1, 1024, 0, stream>>>(pos, rowpart, colpart, (float*)d_out);
}